// Round 1
// baseline (222.600 us; speedup 1.0000x reference)
//
#include <hip/hip_runtime.h>
#include <math.h>

// Problem constants (from reference): B=4, C=2048, V=32000, EPS=0.1
#define BB 4
#define CC 2048
#define VV 32000
#define ROWS (BB * (CC - 1))   // 8188
#define EPSF 0.1f

// ---------------- Kernel A: sum of token_histo -> ws[0] ----------------
__global__ __launch_bounds__(256) void histo_sum_kernel(
    const float* __restrict__ histo, float* __restrict__ ws) {
  __shared__ float sm[256];
  int tid = threadIdx.x;
  float s = 0.0f;
  for (int i = tid; i < VV; i += 256) s += histo[i];
  sm[tid] = s;
  __syncthreads();
  for (int off = 128; off > 0; off >>= 1) {
    if (tid < off) sm[tid] += sm[tid + off];
    __syncthreads();
  }
  if (tid == 0) ws[0] = sm[0];
}

// ---------------- Kernel B: one block per row --------------------------
// Computes xent[row] = lse - 0.9*x[label] - 0.1*dot(histo,x)/S
__global__ __launch_bounds__(256) void row_xent_kernel(
    const int* __restrict__ dec_input,
    const float* __restrict__ dec_output,
    const float* __restrict__ histo,
    const float* __restrict__ ws_s,      // ws[0] = S
    float* __restrict__ row_out) {       // ws+1, ROWS entries
  const int row = blockIdx.x;
  const int b = row / (CC - 1);
  const int c = row % (CC - 1);
  const float* __restrict__ x = dec_output + ((size_t)b * CC + c) * VV;
  const int tid = threadIdx.x;

  float m = -INFINITY;   // running max
  float s = 0.0f;        // running sum of exp(x - m)
  float dot = 0.0f;      // dot(histo, x)

  const float4* __restrict__ x4 = (const float4*)x;
  const float4* __restrict__ h4 = (const float4*)histo;

  // 32000/4 = 8000 float4s, stride 256
  for (int i = tid; i < VV / 4; i += 256) {
    float4 xv = x4[i];
    float4 hv = h4[i];
    dot = fmaf(xv.x, hv.x, dot);
    dot = fmaf(xv.y, hv.y, dot);
    dot = fmaf(xv.z, hv.z, dot);
    dot = fmaf(xv.w, hv.w, dot);
    // group-of-4 online softmax update: 5 exps per 4 elements, branchless
    float lm = fmaxf(fmaxf(xv.x, xv.y), fmaxf(xv.z, xv.w));
    float nm = fmaxf(m, lm);
    s = s * __expf(m - nm)
        + __expf(xv.x - nm) + __expf(xv.y - nm)
        + __expf(xv.z - nm) + __expf(xv.w - nm);
    m = nm;
  }

  // wave (64-lane) butterfly reduce of (m, s) and dot
  for (int off = 1; off < 64; off <<= 1) {
    float om = __shfl_xor(m, off);
    float os = __shfl_xor(s, off);
    float od = __shfl_xor(dot, off);
    float nm = fmaxf(m, om);
    s = s * __expf(m - nm) + os * __expf(om - nm);
    m = nm;
    dot += od;
  }

  // cross-wave combine via LDS (4 waves)
  __shared__ float sm_m[4], sm_s[4], sm_d[4];
  const int wave = tid >> 6;
  if ((tid & 63) == 0) { sm_m[wave] = m; sm_s[wave] = s; sm_d[wave] = dot; }
  __syncthreads();
  if (tid == 0) {
    float M = sm_m[0], Sx = sm_s[0], D = sm_d[0];
    #pragma unroll
    for (int w = 1; w < 4; ++w) {
      float nm = fmaxf(M, sm_m[w]);
      Sx = Sx * __expf(M - nm) + sm_s[w] * __expf(sm_m[w] - nm);
      M = nm;
      D += sm_d[w];
    }
    const float lse = M + __logf(Sx);
    const int label = dec_input[b * CC + c + 1];
    const float xl = x[label];
    const float S = ws_s[0];
    // xent = (1-eps)*(lse - xl) + eps*(lse - D/S)
    row_out[row] = lse - (1.0f - EPSF) * xl - EPSF * (D / S);
  }
}

// ---------------- Kernel C: deterministic mean -> d_out[0] -------------
__global__ __launch_bounds__(256) void final_mean_kernel(
    const float* __restrict__ row_out, float* __restrict__ out) {
  __shared__ float sm[256];
  int tid = threadIdx.x;
  float s = 0.0f;
  for (int i = tid; i < ROWS; i += 256) s += row_out[i];
  sm[tid] = s;
  __syncthreads();
  for (int off = 128; off > 0; off >>= 1) {
    if (tid < off) sm[tid] += sm[tid + off];
    __syncthreads();
  }
  if (tid == 0) out[0] = sm[0] * (1.0f / (float)ROWS);
}

extern "C" void kernel_launch(void* const* d_in, const int* in_sizes, int n_in,
                              void* d_out, int out_size, void* d_ws, size_t ws_size,
                              hipStream_t stream) {
  const int*   dec_input  = (const int*)d_in[0];
  const float* dec_output = (const float*)d_in[1];
  const float* histo      = (const float*)d_in[2];
  float* out = (float*)d_out;
  float* ws  = (float*)d_ws;   // ws[0] = S, ws[1..ROWS] = per-row xent

  histo_sum_kernel<<<1, 256, 0, stream>>>(histo, ws);
  row_xent_kernel<<<ROWS, 256, 0, stream>>>(dec_input, dec_output, histo, ws, ws + 1);
  final_mean_kernel<<<1, 256, 0, stream>>>(ws + 1, out);
}

// Round 3
// 182.346 us; speedup vs baseline: 1.2208x; 1.2208x over previous
//
#include <hip/hip_runtime.h>
#include <math.h>

// Problem constants (from reference): B=4, C=2048, V=32000, EPS=0.1
#define BB 4
#define CC 2048
#define VV 32000
#define ROWS (BB * (CC - 1))   // 8188
#define EPSF 0.1f

typedef float f32x4 __attribute__((ext_vector_type(4)));

// ---------------- Kernel B: one block per row --------------------------
// Computes xent[row] = lse - 0.9*x[label] - 0.1*dot(histo,x)/S
// S = sum(histo) is computed redundantly per block (histo is read anyway).
__global__ __launch_bounds__(256) void row_xent_kernel(
    const int* __restrict__ dec_input,
    const float* __restrict__ dec_output,
    const float* __restrict__ histo,
    float* __restrict__ row_out) {       // ROWS entries
  const int row = blockIdx.x;
  const int b = row / (CC - 1);
  const int c = row % (CC - 1);
  const float* __restrict__ x = dec_output + ((size_t)b * CC + c) * VV;
  const int tid = threadIdx.x;

  // two independent online-softmax states + dot/hsum accumulators
  float m0 = -INFINITY, s0 = 0.0f, d0 = 0.0f;
  float m1 = -INFINITY, s1 = 0.0f, d1 = 0.0f;
  float hs = 0.0f;  // sum of histo

  const f32x4* __restrict__ x4 = (const f32x4*)x;
  const f32x4* __restrict__ h4 = (const f32x4*)histo;

#define CHUNK(I, M, S, D)                                              \
  {                                                                    \
    f32x4 xv = __builtin_nontemporal_load(&x4[I]);                     \
    f32x4 hv = h4[I];                                                  \
    D = fmaf(xv.x, hv.x, D);                                           \
    D = fmaf(xv.y, hv.y, D);                                           \
    D = fmaf(xv.z, hv.z, D);                                           \
    D = fmaf(xv.w, hv.w, D);                                           \
    hs += (hv.x + hv.y) + (hv.z + hv.w);                               \
    float lm = fmaxf(fmaxf(xv.x, xv.y), fmaxf(xv.z, xv.w));            \
    float nm = fmaxf(M, lm);                                           \
    S = S * __expf(M - nm)                                             \
        + __expf(xv.x - nm) + __expf(xv.y - nm)                        \
        + __expf(xv.z - nm) + __expf(xv.w - nm);                       \
    M = nm;                                                            \
  }

  // 32000/4 = 8000 float4s; 2-way unrolled stride-256 walk
  int i = tid;
  for (; i + 256 < VV / 4; i += 512) {
    CHUNK(i, m0, s0, d0);
    CHUNK(i + 256, m1, s1, d1);
  }
  if (i < VV / 4) CHUNK(i, m0, s0, d0);
#undef CHUNK

  // merge the two states; guard s1's m1=-inf never happens (>=15 chunks each)
  float m = fmaxf(m0, m1);
  float s = s0 * __expf(m0 - m) + s1 * __expf(m1 - m);
  float dot = d0 + d1;

  // wave (64-lane) butterfly reduce of (m, s), dot, hs
  for (int off = 1; off < 64; off <<= 1) {
    float om = __shfl_xor(m, off);
    float os = __shfl_xor(s, off);
    float od = __shfl_xor(dot, off);
    float oh = __shfl_xor(hs, off);
    float nm = fmaxf(m, om);
    s = s * __expf(m - nm) + os * __expf(om - nm);
    m = nm;
    dot += od;
    hs += oh;
  }

  // cross-wave combine via LDS (4 waves)
  __shared__ float sm_m[4], sm_s[4], sm_d[4], sm_h[4];
  const int wave = tid >> 6;
  if ((tid & 63) == 0) { sm_m[wave] = m; sm_s[wave] = s; sm_d[wave] = dot; sm_h[wave] = hs; }
  __syncthreads();
  if (tid == 0) {
    float M = sm_m[0], Sx = sm_s[0], D = sm_d[0], H = sm_h[0];
    #pragma unroll
    for (int w = 1; w < 4; ++w) {
      float nm = fmaxf(M, sm_m[w]);
      Sx = Sx * __expf(M - nm) + sm_s[w] * __expf(sm_m[w] - nm);
      M = nm;
      D += sm_d[w];
      H += sm_h[w];
    }
    const float lse = M + __logf(Sx);
    const int label = dec_input[b * CC + c + 1];
    const float xl = x[label];
    // xent = (1-eps)*(lse - xl) + eps*(lse - D/H)
    row_out[row] = lse - (1.0f - EPSF) * xl - EPSF * (D / H);
  }
}

// ---------------- Kernel C: deterministic mean -> d_out[0] -------------
__global__ __launch_bounds__(256) void final_mean_kernel(
    const float* __restrict__ row_out, float* __restrict__ out) {
  __shared__ float sm[256];
  int tid = threadIdx.x;
  float s = 0.0f;
  // ROWS = 8188 = 2047 float4s
  const f32x4* __restrict__ r4 = (const f32x4*)row_out;
  for (int i = tid; i < ROWS / 4; i += 256) {
    f32x4 v = r4[i];
    s += (v.x + v.y) + (v.z + v.w);
  }
  sm[tid] = s;
  __syncthreads();
  for (int off = 128; off > 0; off >>= 1) {
    if (tid < off) sm[tid] += sm[tid + off];
    __syncthreads();
  }
  if (tid == 0) out[0] = sm[0] * (1.0f / (float)ROWS);
}

extern "C" void kernel_launch(void* const* d_in, const int* in_sizes, int n_in,
                              void* d_out, int out_size, void* d_ws, size_t ws_size,
                              hipStream_t stream) {
  const int*   dec_input  = (const int*)d_in[0];
  const float* dec_output = (const float*)d_in[1];
  const float* histo      = (const float*)d_in[2];
  float* out = (float*)d_out;
  float* ws  = (float*)d_ws;   // ws[0..ROWS) = per-row xent (16B-aligned)

  row_xent_kernel<<<ROWS, 256, 0, stream>>>(dec_input, dec_output, histo, ws);
  final_mean_kernel<<<1, 256, 0, stream>>>(ws, out);
}